// Round 1
// baseline (405.436 us; speedup 1.0000x reference)
//
#include <hip/hip_runtime.h>
#include <cstdint>
#include <cmath>

#define RLN2 1.44269504088896340736f

typedef __attribute__((ext_vector_type(8))) short short8;
typedef __attribute__((ext_vector_type(4))) float f32x4;

__device__ __forceinline__ unsigned short f2bf(float f) {
  unsigned int u = __float_as_uint(f);
  u += 0x7fffu + ((u >> 16) & 1u);
  return (unsigned short)(u >> 16);
}

__device__ __forceinline__ float fast_exp2(float x) {
#if __has_builtin(__builtin_amdgcn_exp2f)
  return __builtin_amdgcn_exp2f(x);
#else
  return exp2f(x);
#endif
}

__device__ __forceinline__ void gload16(const void* g, void* l) {
  __builtin_amdgcn_global_load_lds(
      (const __attribute__((address_space(1))) unsigned int*)g,
      (__attribute__((address_space(3))) unsigned int*)l,
      16, 0, 0);
}

// ---------------- fp32 -> bf16 conversions ----------------

__global__ void __launch_bounds__(256) k_cvt_hs(const float* __restrict__ src,
                                                unsigned short* __restrict__ dst) {
  size_t i = (size_t)blockIdx.x * 256 + threadIdx.x;  // 1,048,576 threads, 8 elems each
  const float4* s = (const float4*)src + i * 2;
  float4 a = s[0], b = s[1];
  short8 o;
  o[0] = (short)f2bf(a.x); o[1] = (short)f2bf(a.y); o[2] = (short)f2bf(a.z); o[3] = (short)f2bf(a.w);
  o[4] = (short)f2bf(b.x); o[5] = (short)f2bf(b.y); o[6] = (short)f2bf(b.z); o[7] = (short)f2bf(b.w);
  ((short8*)dst)[i] = o;
}

__global__ void __launch_bounds__(256) k_cvt_w(const float* __restrict__ Wq,
                                               const float* __restrict__ Wk,
                                               const float* __restrict__ Wv,
                                               unsigned short* __restrict__ dst) {
  size_t i = (size_t)blockIdx.x * 256 + threadIdx.x;  // 393,216 threads
  int e = (int)(i * 8);
  int n = e >> 10, c = e & 1023;
  const float* row = (n < 1024) ? (Wq + (size_t)n * 1024)
                   : (n < 2048) ? (Wk + (size_t)(n - 1024) * 1024)
                                : (Wv + (size_t)(n - 2048) * 1024);
  const float4* s = (const float4*)(row + c);
  float4 a = s[0], b = s[1];
  short8 o;
  o[0] = (short)f2bf(a.x); o[1] = (short)f2bf(a.y); o[2] = (short)f2bf(a.z); o[3] = (short)f2bf(a.w);
  o[4] = (short)f2bf(b.x); o[5] = (short)f2bf(b.y); o[6] = (short)f2bf(b.z); o[7] = (short)f2bf(b.w);
  ((short8*)dst)[i] = o;
}

// fill K_aug second half: Kaug[b][h][j][64+d] = seg_table[seg_ids[b,j]][h*64+d]
__global__ void __launch_bounds__(256) k_seg(const int* __restrict__ seg_ids,
                                             const float* __restrict__ seg_table,
                                             unsigned short* __restrict__ Kaug) {
  size_t i = (size_t)blockIdx.x * 256 + threadIdx.x;  // 1,048,576 threads
  int e = (int)(i * 8);
  int jl = e >> 10;   // b*2048 + j
  int r  = e & 1023;  // h*64 + d
  int sid = seg_ids[jl];
  const float4* s = (const float4*)(seg_table + (size_t)sid * 1024 + r);
  float4 a = s[0], b = s[1];
  short8 o;
  o[0] = (short)f2bf(a.x); o[1] = (short)f2bf(a.y); o[2] = (short)f2bf(a.z); o[3] = (short)f2bf(a.w);
  o[4] = (short)f2bf(b.x); o[5] = (short)f2bf(b.y); o[6] = (short)f2bf(b.z); o[7] = (short)f2bf(b.w);
  int b_ = jl >> 11, j = jl & 2047;
  int h = r >> 6, d = r & 63;
  size_t off = ((size_t)(b_ * 16 + h) * 2048 + j) * 128 + 64 + d;
  *(short8*)(Kaug + off) = o;
}

// ---------------- V transpose: [bh][S][64] -> [bh][64][S] ----------------
__global__ void __launch_bounds__(256) k_vt(const unsigned short* __restrict__ V,
                                            unsigned short* __restrict__ Vt) {
  __shared__ unsigned short lt[64 * 72];
  int blk = blockIdx.x;  // bh*32 + jt
  int bh = blk >> 5, jt = blk & 31;
  int j0 = jt * 64;
  int tid = threadIdx.x;
  const char* src = (const char*)(V + ((size_t)bh * 2048 + j0) * 64);
#pragma unroll
  for (int it = 0; it < 2; ++it) {
    int c = tid + it * 256;
    int j = c >> 3, colb = (c & 7) * 16;
    short8 v = *(const short8*)(src + (size_t)j * 128 + colb);
    int d0 = colb >> 1;
#pragma unroll
    for (int e = 0; e < 8; ++e)
      lt[(d0 + e) * 72 + j] = (unsigned short)v[e];
  }
  __syncthreads();
  char* dst = (char*)(Vt + (size_t)bh * 131072 + j0);
#pragma unroll
  for (int it = 0; it < 2; ++it) {
    int c = tid + it * 256;
    int d = c >> 3, jc = (c & 7) * 8;
    short8 o = *(const short8*)&lt[d * 72 + jc];
    *(short8*)(dst + (size_t)d * 4096 + jc * 2) = o;
  }
}

// ---------------- fused QKV GEMM (NT): C[8192][3072] = hs_bf16 . Wcat^T ----------------
// epilogue scatters to Qaug (scaled + bias-augmented halves), Kaug (first half), V
__global__ void __launch_bounds__(256) k_gemm(const unsigned short* __restrict__ A,
                                              const unsigned short* __restrict__ Bw,
                                              const float* __restrict__ bq,
                                              const float* __restrict__ bv,
                                              const float* __restrict__ bqs,
                                              unsigned short* __restrict__ Qaug,
                                              unsigned short* __restrict__ Kaug,
                                              unsigned short* __restrict__ Vo) {
  __shared__ unsigned short As[128 * 32];
  __shared__ unsigned short Bs[128 * 32];
  int n0 = blockIdx.x * 128;
  int m0 = blockIdx.y * 128;
  int tid = threadIdx.x;
  int w = tid >> 6, lane = tid & 63;
  int wr = (w >> 1) * 64, wc = (w & 1) * 64;
  int rA = lane & 15;
  int kg = (lane >> 4) * 16;
  f32x4 acc[4][4] = {};
  const char* Ab = (const char*)A;
  const char* Bb = (const char*)Bw;

  for (int kt = 0; kt < 32; ++kt) {
    int kb0 = kt * 64;  // byte offset of k-slab within a 2048-byte row
#pragma unroll
    for (int c = 0; c < 2; ++c) {
      int chunk = w * 2 + c;
      int y = chunk * 1024 + lane * 16;
      int row = y >> 6, colb = y & 63;
      gload16(Ab + (size_t)(m0 + row) * 2048 + kb0 + colb, (char*)As + chunk * 1024);
      gload16(Bb + (size_t)(n0 + row) * 2048 + kb0 + colb, (char*)Bs + chunk * 1024);
    }
    __syncthreads();
    short8 af[4], bfr[4];
#pragma unroll
    for (int m = 0; m < 4; ++m)
      af[m] = *(const short8*)((const char*)As + (wr + m * 16 + rA) * 64 + kg);
#pragma unroll
    for (int n = 0; n < 4; ++n)
      bfr[n] = *(const short8*)((const char*)Bs + (wc + n * 16 + rA) * 64 + kg);
#pragma unroll
    for (int m = 0; m < 4; ++m)
#pragma unroll
      for (int n = 0; n < 4; ++n)
        acc[m][n] = __builtin_amdgcn_mfma_f32_16x16x32_bf16(af[m], bfr[n], acc[m][n], 0, 0, 0);
    __syncthreads();
  }

  int seg = n0 >> 10;        // 0=q, 1=k, 2=v (128-tiles never straddle)
  int colbase = n0 & 1023;
#pragma unroll
  for (int n = 0; n < 4; ++n) {
    int o = colbase + wc + n * 16 + (lane & 15);
    int h = o >> 6, d = o & 63;
    float bias = 0.f, bqsv = 0.f;
    if (seg == 0) { bias = bq[o]; bqsv = bqs[o]; }
    else if (seg == 2) { bias = bv[o]; }
#pragma unroll
    for (int m = 0; m < 4; ++m) {
#pragma unroll
      for (int r = 0; r < 4; ++r) {
        int i = m0 + wr + m * 16 + (lane >> 4) * 4 + r;
        int b_ = i >> 11, sdx = i & 2047;
        float val = acc[m][n][r];
        size_t tok = (size_t)(b_ * 16 + h) * 2048 + sdx;
        if (seg == 0) {
          float qv = val + bias;
          Qaug[tok * 128 + d]      = f2bf(qv * (0.125f * RLN2));
          Qaug[tok * 128 + 64 + d] = f2bf((qv + bqsv) * RLN2);
        } else if (seg == 1) {
          Kaug[tok * 128 + d] = f2bf(val);
        } else {
          Vo[tok * 64 + d] = f2bf(val + bias);
        }
      }
    }
  }
}

// ---------------- flash attention, head-dim 128 (augmented), DV=64 ----------------
__global__ void __launch_bounds__(256) k_attn(const unsigned short* __restrict__ Qaug,
                                              const unsigned short* __restrict__ Kaug,
                                              const unsigned short* __restrict__ Vt,
                                              const float* __restrict__ mask,
                                              float* __restrict__ out) {
  __shared__ char smem[65536];
  char* Qsb = smem;          // [0,16K) Q tile, reused as P after qf extraction
  char* Psb = smem;          // per-wave 2KB at w*2048
  char* Ksb = smem + 16384;  // double buf: +cur*16384, [16K,48K)
  char* Vsb = smem + 49152;  // double buf: +cur*8192,  [48K,64K)

  int qt = blockIdx.x, h = blockIdx.y, b_ = blockIdx.z;
  int bh = b_ * 16 + h;
  int i0 = qt * 64;
  int tid = threadIdx.x, w = tid >> 6, lane = tid & 63;
  const char* Qg = (const char*)Qaug + (size_t)bh * 2048 * 256;
  const char* Kg = (const char*)Kaug + (size_t)bh * 2048 * 256;
  const char* Vg = (const char*)Vt + (size_t)bh * 64 * 4096;
  const float* maskb = mask + (size_t)b_ * 2048;

  // stage Q tile [64][128] bf16, pre-swizzled source so swizzled reads are conflict-free
#pragma unroll
  for (int c = 0; c < 4; ++c) {
    int chunk = w * 4 + c;
    int y = chunk * 1024 + lane * 16;
    int ys = y ^ (((y >> 8) & 7) << 4);
    gload16(Qg + (size_t)(i0 + (y >> 8)) * 256 + (ys & 255), Qsb + chunk * 1024);
  }
  // stage K/V tile 0 into buffer 0
#pragma unroll
  for (int c = 0; c < 4; ++c) {
    int chunk = w * 4 + c;
    int y = chunk * 1024 + lane * 16;
    int ys = y ^ (((y >> 8) & 7) << 4);
    gload16(Kg + (size_t)(y >> 8) * 256 + (ys & 255), Ksb + chunk * 1024);
  }
#pragma unroll
  for (int c = 0; c < 2; ++c) {
    int chunk = w * 2 + c;
    int y = chunk * 1024 + lane * 16;
    int ys = y ^ (((y >> 7) & 7) << 4);
    gload16(Vg + (size_t)(y >> 7) * 4096 + (ys & 127), Vsb + chunk * 1024);
  }
  __syncthreads();  // Q, K0, V0 resident

  short8 qf[4];
  {
    int row = w * 16 + (lane & 15);
#pragma unroll
    for (int db = 0; db < 4; ++db) {
      int off = (row * 256 + db * 64 + (lane >> 4) * 16) ^ ((row & 7) << 4);
      qf[db] = *(const short8*)(Qsb + off);
    }
  }
  __syncthreads();  // qf in registers everywhere before Qs region is reused as P

  float m_r[4], l_r[4];
#pragma unroll
  for (int r = 0; r < 4; ++r) { m_r[r] = -1e30f; l_r[r] = 0.f; }
  f32x4 accO[4] = {};

  for (int t = 0; t < 32; ++t) {
    int cur = t & 1, nxt = cur ^ 1;
    int j0 = t * 64;
    if (t < 31) {  // prefetch next K/V tile into the other buffer
      int jn = j0 + 64;
      char* kd = Ksb + nxt * 16384;
      char* vd = Vsb + nxt * 8192;
#pragma unroll
      for (int c = 0; c < 4; ++c) {
        int chunk = w * 4 + c;
        int y = chunk * 1024 + lane * 16;
        int ys = y ^ (((y >> 8) & 7) << 4);
        gload16(Kg + (size_t)(jn + (y >> 8)) * 256 + (ys & 255), kd + chunk * 1024);
      }
#pragma unroll
      for (int c = 0; c < 2; ++c) {
        int chunk = w * 2 + c;
        int y = chunk * 1024 + lane * 16;
        int ys = y ^ (((y >> 7) & 7) << 4);
        gload16(Vg + (size_t)(y >> 7) * 4096 + (size_t)jn * 2 + (ys & 127), vd + chunk * 1024);
      }
    }
    const char* kb_ = Ksb + cur * 16384;
    const char* vb_ = Vsb + cur * 8192;

    // S = Qaug . Kaug^T  (16 q-rows x 64 kv-cols per wave)
    f32x4 s[4] = {};
#pragma unroll
    for (int jb = 0; jb < 4; ++jb) {
      int krow = jb * 16 + (lane & 15);
#pragma unroll
      for (int db = 0; db < 4; ++db) {
        int off = (krow * 256 + db * 64 + (lane >> 4) * 16) ^ ((krow & 7) << 4);
        short8 kf = *(const short8*)(kb_ + off);
        s[jb] = __builtin_amdgcn_mfma_f32_16x16x32_bf16(qf[db], kf, s[jb], 0, 0, 0);
      }
    }
    // + attention_mask (broadcast over rows), already in log2 domain
#pragma unroll
    for (int jb = 0; jb < 4; ++jb) {
      float mv = maskb[j0 + jb * 16 + (lane & 15)] * RLN2;
      s[jb][0] += mv; s[jb][1] += mv; s[jb][2] += mv; s[jb][3] += mv;
    }
    // online softmax (rows owned by 16-lane groups; reduce via shfl_xor 1/2/4/8)
    float alpha[4];
#pragma unroll
    for (int r = 0; r < 4; ++r) {
      float tm = fmaxf(fmaxf(s[0][r], s[1][r]), fmaxf(s[2][r], s[3][r]));
      tm = fmaxf(tm, __shfl_xor(tm, 1));
      tm = fmaxf(tm, __shfl_xor(tm, 2));
      tm = fmaxf(tm, __shfl_xor(tm, 4));
      tm = fmaxf(tm, __shfl_xor(tm, 8));
      float mn = fmaxf(m_r[r], tm);
      float al = fast_exp2(m_r[r] - mn);
      m_r[r] = mn; alpha[r] = al;
      float psum = 0.f;
#pragma unroll
      for (int jb = 0; jb < 4; ++jb) {
        float p = fast_exp2(s[jb][r] - mn);
        s[jb][r] = p;
        psum += p;
      }
      psum += __shfl_xor(psum, 1);
      psum += __shfl_xor(psum, 2);
      psum += __shfl_xor(psum, 4);
      psum += __shfl_xor(psum, 8);
      l_r[r] = l_r[r] * al + psum;
    }
#pragma unroll
    for (int nb = 0; nb < 4; ++nb)
#pragma unroll
      for (int r = 0; r < 4; ++r)
        accO[nb][r] *= alpha[r];

    // stage P (bf16) into wave-private LDS in A-operand layout (swizzled rows)
    {
      char* pw = Psb + w * 2048;
#pragma unroll
      for (int jb = 0; jb < 4; ++jb) {
        int col = jb * 16 + (lane & 15);
#pragma unroll
        for (int r = 0; r < 4; ++r) {
          int row = (lane >> 4) * 4 + r;
          int off = (row * 128 + col * 2) ^ ((row & 7) << 4);
          *(unsigned short*)(pw + off) = f2bf(s[jb][r]);
        }
      }
    }
    asm volatile("s_waitcnt lgkmcnt(0)" ::: "memory");
    // O += P . V  (contract over 64 kv, two K=32 slabs)
    {
      const char* pw = Psb + w * 2048;
      int prow = lane & 15;
      short8 pf[2];
#pragma unroll
      for (int kb = 0; kb < 2; ++kb) {
        int off = (prow * 128 + kb * 64 + (lane >> 4) * 16) ^ ((prow & 7) << 4);
        pf[kb] = *(const short8*)(pw + off);
      }
#pragma unroll
      for (int nb = 0; nb < 4; ++nb) {
        int vrow = nb * 16 + (lane & 15);
#pragma unroll
        for (int kb = 0; kb < 2; ++kb) {
          int off = (vrow * 128 + kb * 64 + (lane >> 4) * 16) ^ ((vrow & 7) << 4);
          short8 vf = *(const short8*)(vb_ + off);
          accO[nb] = __builtin_amdgcn_mfma_f32_16x16x32_bf16(pf[kb], vf, accO[nb], 0, 0, 0);
        }
      }
    }
    __syncthreads();  // drains next-tile staging; all waves done with current buffers
  }

#pragma unroll
  for (int nb = 0; nb < 4; ++nb) {
    int dv = nb * 16 + (lane & 15);
#pragma unroll
    for (int r = 0; r < 4; ++r) {
      int i = i0 + w * 16 + (lane >> 4) * 4 + r;
      out[((size_t)b_ * 2048 + i) * 1024 + h * 64 + dv] = accO[nb][r] / l_r[r];
    }
  }
}

extern "C" void kernel_launch(void* const* d_in, const int* in_sizes, int n_in,
                              void* d_out, int out_size, void* d_ws, size_t ws_size,
                              hipStream_t stream) {
  (void)in_sizes; (void)n_in; (void)out_size; (void)ws_size;
  const float* hs        = (const float*)d_in[0];
  const float* mask      = (const float*)d_in[1];
  const int*   seg_ids   = (const int*)d_in[2];
  const float* Wq        = (const float*)d_in[3];
  const float* bq        = (const float*)d_in[4];
  const float* Wk        = (const float*)d_in[5];
  const float* Wv        = (const float*)d_in[6];
  const float* bv        = (const float*)d_in[7];
  const float* seg_table = (const float*)d_in[8];
  const float* bqs       = (const float*)d_in[9];
  float* out = (float*)d_out;
  char* ws = (char*)d_ws;

  // workspace layout (bytes): total 102 MiB; Vt overlays hs_bf16 (dead after GEMM)
  unsigned short* hsb  = (unsigned short*)(ws + 0);         // 16 MiB
  unsigned short* Wcat = (unsigned short*)(ws + 16777216);  // 6 MiB
  unsigned short* Qaug = (unsigned short*)(ws + 23068672);  // 32 MiB
  unsigned short* Kaug = (unsigned short*)(ws + 56623104);  // 32 MiB
  unsigned short* V    = (unsigned short*)(ws + 90177536);  // 16 MiB
  unsigned short* Vt   = (unsigned short*)(ws + 0);         // reuse

  k_cvt_hs<<<dim3(4096), dim3(256), 0, stream>>>(hs, hsb);
  k_cvt_w<<<dim3(1536), dim3(256), 0, stream>>>(Wq, Wk, Wv, Wcat);
  k_gemm<<<dim3(24, 64), dim3(256), 0, stream>>>(hsb, Wcat, bq, bv, bqs, Qaug, Kaug, V);
  k_seg<<<dim3(4096), dim3(256), 0, stream>>>(seg_ids, seg_table, Kaug);
  k_vt<<<dim3(2048), dim3(256), 0, stream>>>(V, Vt);
  k_attn<<<dim3(32, 16, 4), dim3(256), 0, stream>>>(Qaug, Kaug, Vt, mask, out);
}

// Round 2
// 313.029 us; speedup vs baseline: 1.2952x; 1.2952x over previous
//
#include <hip/hip_runtime.h>
#include <cstdint>
#include <cmath>

#define RLN2 1.44269504088896340736f

typedef __attribute__((ext_vector_type(8))) short short8;
typedef __attribute__((ext_vector_type(4))) float f32x4;
typedef __attribute__((ext_vector_type(4))) unsigned int uint4v;
typedef __attribute__((ext_vector_type(2))) unsigned int uint2v;

__device__ __forceinline__ unsigned short f2bf(float f) {
  unsigned int u = __float_as_uint(f);
  u += 0x7fffu + ((u >> 16) & 1u);
  return (unsigned short)(u >> 16);
}

__device__ __forceinline__ float fast_exp2(float x) {
#if __has_builtin(__builtin_amdgcn_exp2f)
  return __builtin_amdgcn_exp2f(x);
#else
  return exp2f(x);
#endif
}

__device__ __forceinline__ void gload16(const void* g, void* l) {
  __builtin_amdgcn_global_load_lds(
      (const __attribute__((address_space(1))) unsigned int*)g,
      (__attribute__((address_space(3))) unsigned int*)l,
      16, 0, 0);
}

// ---------------- fp32 -> bf16 conversions ----------------

__global__ void __launch_bounds__(256) k_cvt_hs(const float* __restrict__ src,
                                                unsigned short* __restrict__ dst) {
  size_t i = (size_t)blockIdx.x * 256 + threadIdx.x;
  const float4* s = (const float4*)src + i * 2;
  float4 a = s[0], b = s[1];
  short8 o;
  o[0] = (short)f2bf(a.x); o[1] = (short)f2bf(a.y); o[2] = (short)f2bf(a.z); o[3] = (short)f2bf(a.w);
  o[4] = (short)f2bf(b.x); o[5] = (short)f2bf(b.y); o[6] = (short)f2bf(b.z); o[7] = (short)f2bf(b.w);
  ((short8*)dst)[i] = o;
}

__global__ void __launch_bounds__(256) k_cvt_w(const float* __restrict__ Wq,
                                               const float* __restrict__ Wk,
                                               const float* __restrict__ Wv,
                                               unsigned short* __restrict__ dst) {
  size_t i = (size_t)blockIdx.x * 256 + threadIdx.x;
  int e = (int)(i * 8);
  int n = e >> 10, c = e & 1023;
  const float* row = (n < 1024) ? (Wq + (size_t)n * 1024)
                   : (n < 2048) ? (Wk + (size_t)(n - 1024) * 1024)
                                : (Wv + (size_t)(n - 2048) * 1024);
  const float4* s = (const float4*)(row + c);
  float4 a = s[0], b = s[1];
  short8 o;
  o[0] = (short)f2bf(a.x); o[1] = (short)f2bf(a.y); o[2] = (short)f2bf(a.z); o[3] = (short)f2bf(a.w);
  o[4] = (short)f2bf(b.x); o[5] = (short)f2bf(b.y); o[6] = (short)f2bf(b.z); o[7] = (short)f2bf(b.w);
  ((short8*)dst)[i] = o;
}

__global__ void __launch_bounds__(256) k_seg(const int* __restrict__ seg_ids,
                                             const float* __restrict__ seg_table,
                                             unsigned short* __restrict__ Kaug) {
  size_t i = (size_t)blockIdx.x * 256 + threadIdx.x;
  int e = (int)(i * 8);
  int jl = e >> 10;
  int r  = e & 1023;
  int sid = seg_ids[jl];
  const float4* s = (const float4*)(seg_table + (size_t)sid * 1024 + r);
  float4 a = s[0], b = s[1];
  short8 o;
  o[0] = (short)f2bf(a.x); o[1] = (short)f2bf(a.y); o[2] = (short)f2bf(a.z); o[3] = (short)f2bf(a.w);
  o[4] = (short)f2bf(b.x); o[5] = (short)f2bf(b.y); o[6] = (short)f2bf(b.z); o[7] = (short)f2bf(b.w);
  int b_ = jl >> 11, j = jl & 2047;
  int h = r >> 6, d = r & 63;
  size_t off = ((size_t)(b_ * 16 + h) * 2048 + j) * 128 + 64 + d;
  *(short8*)(Kaug + off) = o;
}

// ---------------- V transpose: [bh][S][64] -> [bh][64][S] ----------------
__global__ void __launch_bounds__(256) k_vt(const unsigned short* __restrict__ V,
                                            unsigned short* __restrict__ Vt) {
  __shared__ unsigned short lt[64 * 72];
  int blk = blockIdx.x;
  int bh = blk >> 5, jt = blk & 31;
  int j0 = jt * 64;
  int tid = threadIdx.x;
  const char* src = (const char*)(V + ((size_t)bh * 2048 + j0) * 64);
#pragma unroll
  for (int it = 0; it < 2; ++it) {
    int c = tid + it * 256;
    int j = c >> 3, colb = (c & 7) * 16;
    short8 v = *(const short8*)(src + (size_t)j * 128 + colb);
    int d0 = colb >> 1;
#pragma unroll
    for (int e = 0; e < 8; ++e)
      lt[(d0 + e) * 72 + j] = (unsigned short)v[e];
  }
  __syncthreads();
  char* dst = (char*)(Vt + (size_t)bh * 131072 + j0);
#pragma unroll
  for (int it = 0; it < 2; ++it) {
    int c = tid + it * 256;
    int d = c >> 3, jc = (c & 7) * 8;
    short8 o = *(const short8*)&lt[d * 72 + jc];
    *(short8*)(dst + (size_t)d * 4096 + jc * 2) = o;
  }
}

// ---------------- fused QKV GEMM (NT) ----------------
__global__ void __launch_bounds__(256) k_gemm(const unsigned short* __restrict__ A,
                                              const unsigned short* __restrict__ Bw,
                                              const float* __restrict__ bq,
                                              const float* __restrict__ bv,
                                              const float* __restrict__ bqs,
                                              unsigned short* __restrict__ Qaug,
                                              unsigned short* __restrict__ Kaug,
                                              unsigned short* __restrict__ Vo) {
  __shared__ unsigned short As[128 * 32];
  __shared__ unsigned short Bs[128 * 32];
  int n0 = blockIdx.x * 128;
  int m0 = blockIdx.y * 128;
  int tid = threadIdx.x;
  int w = tid >> 6, lane = tid & 63;
  int wr = (w >> 1) * 64, wc = (w & 1) * 64;
  int rA = lane & 15;
  int kg = (lane >> 4) * 16;
  f32x4 acc[4][4] = {};
  const char* Ab = (const char*)A;
  const char* Bb = (const char*)Bw;

  for (int kt = 0; kt < 32; ++kt) {
    int kb0 = kt * 64;
#pragma unroll
    for (int c = 0; c < 2; ++c) {
      int chunk = w * 2 + c;
      int y = chunk * 1024 + lane * 16;
      int row = y >> 6, colb = y & 63;
      gload16(Ab + (size_t)(m0 + row) * 2048 + kb0 + colb, (char*)As + chunk * 1024);
      gload16(Bb + (size_t)(n0 + row) * 2048 + kb0 + colb, (char*)Bs + chunk * 1024);
    }
    __syncthreads();
    short8 af[4], bfr[4];
#pragma unroll
    for (int m = 0; m < 4; ++m)
      af[m] = *(const short8*)((const char*)As + (wr + m * 16 + rA) * 64 + kg);
#pragma unroll
    for (int n = 0; n < 4; ++n)
      bfr[n] = *(const short8*)((const char*)Bs + (wc + n * 16 + rA) * 64 + kg);
#pragma unroll
    for (int m = 0; m < 4; ++m)
#pragma unroll
      for (int n = 0; n < 4; ++n)
        acc[m][n] = __builtin_amdgcn_mfma_f32_16x16x32_bf16(af[m], bfr[n], acc[m][n], 0, 0, 0);
    __syncthreads();
  }

  int seg = n0 >> 10;
  int colbase = n0 & 1023;
#pragma unroll
  for (int n = 0; n < 4; ++n) {
    int o = colbase + wc + n * 16 + (lane & 15);
    int h = o >> 6, d = o & 63;
    float bias = 0.f, bqsv = 0.f;
    if (seg == 0) { bias = bq[o]; bqsv = bqs[o]; }
    else if (seg == 2) { bias = bv[o]; }
#pragma unroll
    for (int m = 0; m < 4; ++m) {
#pragma unroll
      for (int r = 0; r < 4; ++r) {
        int i = m0 + wr + m * 16 + (lane >> 4) * 4 + r;
        int b_ = i >> 11, sdx = i & 2047;
        float val = acc[m][n][r];
        size_t tok = (size_t)(b_ * 16 + h) * 2048 + sdx;
        if (seg == 0) {
          float qv = val + bias;
          Qaug[tok * 128 + d]      = f2bf(qv * (0.125f * RLN2));
          Qaug[tok * 128 + 64 + d] = f2bf((qv + bqsv) * RLN2);
        } else if (seg == 1) {
          Kaug[tok * 128 + d] = f2bf(val);
        } else {
          Vo[tok * 64 + d] = f2bf(val + bias);
        }
      }
    }
  }
}

// ---------------- flash attention, swapped-QK^T lane-local softmax ----------------
// S^T layout: lane owns q = lane&15; regs s[jb][r] hold k = jb*16 + g*4 + r (g = lane>>4).
// PV uses a consistent permutation of the MFMA contraction axis:
//   pi(kk) = 16*((kk&7)>>2) + 4*(kk>>3) + (kk&3)  (bijection on [0,32))
// so P packs into the A-fragment with NO cross-lane ops; V's B-fragment reads two b64
// chunks per row at the pi-permuted offsets.
__global__ void __launch_bounds__(256, 3) k_attn(const unsigned short* __restrict__ Qaug,
                                                 const unsigned short* __restrict__ Kaug,
                                                 const unsigned short* __restrict__ Vt,
                                                 const float* __restrict__ mask,
                                                 float* __restrict__ out) {
  __shared__ char smem[49152];
  char* Ksb = smem;          // double buf: 2 x 16K
  char* Vsb = smem + 32768;  // double buf: 2 x 8K

  int qt = blockIdx.x, h = blockIdx.y, b_ = blockIdx.z;
  int bh = b_ * 16 + h;
  int i0 = qt * 64;
  int tid = threadIdx.x, w = tid >> 6, lane = tid & 63;
  int q16 = lane & 15, g = lane >> 4;
  const char* Qg = (const char*)Qaug + (size_t)bh * 2048 * 256;
  const char* Kg = (const char*)Kaug + (size_t)bh * 2048 * 256;
  const char* Vg = (const char*)Vt + (size_t)bh * 64 * 4096;
  const float* maskb = mask + (size_t)b_ * 2048;

  // stage K/V tile 0 into buffer 0 (pre-swizzled global source, linear LDS dest)
#pragma unroll
  for (int c = 0; c < 4; ++c) {
    int chunk = w * 4 + c;
    int y = chunk * 1024 + lane * 16;
    int ys = y ^ (((y >> 8) & 7) << 4);
    gload16(Kg + (size_t)(y >> 8) * 256 + (ys & 255), Ksb + chunk * 1024);
  }
#pragma unroll
  for (int c = 0; c < 2; ++c) {
    int chunk = w * 2 + c;
    int y = chunk * 1024 + lane * 16;
    int ys = y ^ (((y >> 7) & 7) << 4);
    gload16(Vg + (size_t)(y >> 7) * 4096 + (ys & 127), Vsb + chunk * 1024);
  }

  // Q fragments (B-operand) straight from global: row = i0 + w*16 + q16, 8 elems at g*8
  short8 qf[4];
  {
    const char* qrow = Qg + (size_t)(i0 + w * 16 + q16) * 256 + g * 16;
#pragma unroll
    for (int db = 0; db < 4; ++db)
      qf[db] = *(const short8*)(qrow + db * 64);
  }
  __syncthreads();  // K0/V0 resident (syncthreads drains vmcnt)

  float m_run = -1e30f, l_run = 0.f;
  f32x4 accO[4] = {};

  for (int t = 0; t < 32; ++t) {
    int cur = t & 1, nxt = cur ^ 1;
    int j0 = t * 64;
    if (t < 31) {
      int jn = j0 + 64;
      char* kd = Ksb + nxt * 16384;
      char* vd = Vsb + nxt * 8192;
#pragma unroll
      for (int c = 0; c < 4; ++c) {
        int chunk = w * 4 + c;
        int y = chunk * 1024 + lane * 16;
        int ys = y ^ (((y >> 8) & 7) << 4);
        gload16(Kg + (size_t)(jn + (y >> 8)) * 256 + (ys & 255), kd + chunk * 1024);
      }
#pragma unroll
      for (int c = 0; c < 2; ++c) {
        int chunk = w * 2 + c;
        int y = chunk * 1024 + lane * 16;
        int ys = y ^ (((y >> 7) & 7) << 4);
        gload16(Vg + (size_t)(y >> 7) * 4096 + (size_t)jn * 2 + (ys & 127), vd + chunk * 1024);
      }
    }
    const char* kb_ = Ksb + cur * 16384;
    const char* vb_ = Vsb + cur * 8192;

    // S^T = K_aug . Q_aug^T : A = K rows (16 per jb), B = Q rows (this wave's 16)
    f32x4 s[4] = {};
#pragma unroll
    for (int jb = 0; jb < 4; ++jb) {
      int krow = jb * 16 + q16;
      int swz = (krow & 7) << 4;
#pragma unroll
      for (int db = 0; db < 4; ++db) {
        short8 kf = *(const short8*)(kb_ + ((krow * 256 + db * 64 + g * 16) ^ swz));
        s[jb] = __builtin_amdgcn_mfma_f32_16x16x32_bf16(kf, qf[db], s[jb], 0, 0, 0);
      }
    }

    // + attention_mask: s[jb][r] is k = j0 + jb*16 + g*4 + r -> contiguous float4 per jb
#pragma unroll
    for (int jb = 0; jb < 4; ++jb) {
      float4 mv = *(const float4*)(maskb + j0 + jb * 16 + g * 4);
      s[jb][0] += mv.x * RLN2; s[jb][1] += mv.y * RLN2;
      s[jb][2] += mv.z * RLN2; s[jb][3] += mv.w * RLN2;
    }

    // lane-local softmax over this lane's 16 k-values, reduce across g (xor 16,32)
    float tm = -1e30f;
#pragma unroll
    for (int jb = 0; jb < 4; ++jb)
      tm = fmaxf(tm, fmaxf(fmaxf(s[jb][0], s[jb][1]), fmaxf(s[jb][2], s[jb][3])));
    tm = fmaxf(tm, __shfl_xor(tm, 16));
    tm = fmaxf(tm, __shfl_xor(tm, 32));

    // defer-max (T13, THR=8 in log2 domain): skip rescale unless max grew past threshold
    if (__any(tm > m_run + 8.0f)) {
      float mn = fmaxf(m_run, tm);
      float alpha = fast_exp2(m_run - mn);
      m_run = mn;
      l_run *= alpha;
      float al[4];
#pragma unroll
      for (int r = 0; r < 4; ++r)
        al[r] = __shfl(alpha, (lane & 48) + g * 4 + r);  // src owns q-row g*4+r
#pragma unroll
      for (int nb = 0; nb < 4; ++nb) {
        accO[nb][0] *= al[0]; accO[nb][1] *= al[1];
        accO[nb][2] *= al[2]; accO[nb][3] *= al[3];
      }
    }

    float ps = 0.f;
#pragma unroll
    for (int jb = 0; jb < 4; ++jb)
#pragma unroll
      for (int r = 0; r < 4; ++r) {
        float p = fast_exp2(s[jb][r] - m_run);
        s[jb][r] = p;
        ps += p;
      }
    ps += __shfl_xor(ps, 16);
    ps += __shfl_xor(ps, 32);
    l_run += ps;

    // pack P to bf16 pairs (static indexing throughout)
    unsigned int pk[4][2];
#pragma unroll
    for (int jb = 0; jb < 4; ++jb) {
#pragma unroll
      for (int hh = 0; hh < 2; ++hh)
        pk[jb][hh] = (unsigned int)f2bf(s[jb][2 * hh]) |
                     ((unsigned int)f2bf(s[jb][2 * hh + 1]) << 16);
    }

    // O += P . V over the pi-permuted contraction axis
#pragma unroll
    for (int kb = 0; kb < 2; ++kb) {
      uint4v pw;
      pw[0] = pk[2 * kb][0]; pw[1] = pk[2 * kb][1];
      pw[2] = pk[2 * kb + 1][0]; pw[3] = pk[2 * kb + 1][1];
      short8 pf = __builtin_bit_cast(short8, pw);
#pragma unroll
      for (int nb = 0; nb < 4; ++nb) {
        int vrow = nb * 16 + q16;
        int vswz = (vrow & 7) << 4;
        uint2v va = *(const uint2v*)(vb_ + ((vrow * 128 + kb * 64 + g * 8) ^ vswz));
        uint2v vbq = *(const uint2v*)(vb_ + ((vrow * 128 + kb * 64 + 32 + g * 8) ^ vswz));
        uint4v vw; vw[0] = va[0]; vw[1] = va[1]; vw[2] = vbq[0]; vw[3] = vbq[1];
        short8 vf = __builtin_bit_cast(short8, vw);
        accO[nb] = __builtin_amdgcn_mfma_f32_16x16x32_bf16(pf, vf, accO[nb], 0, 0, 0);
      }
    }
    __syncthreads();  // prefetch drained; buffers swap
  }

  float lr[4];
#pragma unroll
  for (int r = 0; r < 4; ++r)
    lr[r] = __shfl(l_run, (lane & 48) + g * 4 + r);
#pragma unroll
  for (int nb = 0; nb < 4; ++nb) {
    int dv = nb * 16 + q16;
#pragma unroll
    for (int r = 0; r < 4; ++r) {
      int i = i0 + w * 16 + g * 4 + r;
      out[((size_t)b_ * 2048 + i) * 1024 + h * 64 + dv] = accO[nb][r] / lr[r];
    }
  }
}

extern "C" void kernel_launch(void* const* d_in, const int* in_sizes, int n_in,
                              void* d_out, int out_size, void* d_ws, size_t ws_size,
                              hipStream_t stream) {
  (void)in_sizes; (void)n_in; (void)out_size; (void)ws_size;
  const float* hs        = (const float*)d_in[0];
  const float* mask      = (const float*)d_in[1];
  const int*   seg_ids   = (const int*)d_in[2];
  const float* Wq        = (const float*)d_in[3];
  const float* bq        = (const float*)d_in[4];
  const float* Wk        = (const float*)d_in[5];
  const float* Wv        = (const float*)d_in[6];
  const float* bv        = (const float*)d_in[7];
  const float* seg_table = (const float*)d_in[8];
  const float* bqs       = (const float*)d_in[9];
  float* out = (float*)d_out;
  char* ws = (char*)d_ws;

  unsigned short* hsb  = (unsigned short*)(ws + 0);         // 16 MiB
  unsigned short* Wcat = (unsigned short*)(ws + 16777216);  // 6 MiB
  unsigned short* Qaug = (unsigned short*)(ws + 23068672);  // 32 MiB
  unsigned short* Kaug = (unsigned short*)(ws + 56623104);  // 32 MiB
  unsigned short* V    = (unsigned short*)(ws + 90177536);  // 16 MiB
  unsigned short* Vt   = (unsigned short*)(ws + 0);         // reuse (hsb dead after GEMM)

  k_cvt_hs<<<dim3(4096), dim3(256), 0, stream>>>(hs, hsb);
  k_cvt_w<<<dim3(1536), dim3(256), 0, stream>>>(Wq, Wk, Wv, Wcat);
  k_gemm<<<dim3(24, 64), dim3(256), 0, stream>>>(hsb, Wcat, bq, bv, bqs, Qaug, Kaug, V);
  k_seg<<<dim3(4096), dim3(256), 0, stream>>>(seg_ids, seg_table, Kaug);
  k_vt<<<dim3(2048), dim3(256), 0, stream>>>(V, Vt);
  k_attn<<<dim3(32, 16, 4), dim3(256), 0, stream>>>(Qaug, Kaug, Vt, mask, out);
}

// Round 3
// 297.666 us; speedup vs baseline: 1.3621x; 1.0516x over previous
//
#include <hip/hip_runtime.h>
#include <cstdint>
#include <cmath>

#define RLN2 1.44269504088896340736f

typedef __attribute__((ext_vector_type(8))) short short8;
typedef __attribute__((ext_vector_type(4))) float f32x4;
typedef __attribute__((ext_vector_type(4))) unsigned int uint4v;

__device__ __forceinline__ unsigned short f2bf(float f) {
  unsigned int u = __float_as_uint(f);
  u += 0x7fffu + ((u >> 16) & 1u);
  return (unsigned short)(u >> 16);
}

__device__ __forceinline__ unsigned int cvt_pk_bf16(float lo, float hi) {
  unsigned int r;
  asm("v_cvt_pk_bf16_f32 %0, %1, %2" : "=v"(r) : "v"(lo), "v"(hi));
  return r;
}

__device__ __forceinline__ float fast_exp2(float x) {
#if __has_builtin(__builtin_amdgcn_exp2f)
  return __builtin_amdgcn_exp2f(x);
#else
  return exp2f(x);
#endif
}

__device__ __forceinline__ void gload16(const void* g, void* l) {
  __builtin_amdgcn_global_load_lds(
      (const __attribute__((address_space(1))) unsigned int*)g,
      (__attribute__((address_space(3))) unsigned int*)l,
      16, 0, 0);
}

// ---------------- fp32 -> bf16 conversions ----------------

__global__ void __launch_bounds__(256) k_cvt_hs(const float* __restrict__ src,
                                                unsigned short* __restrict__ dst) {
  size_t i = (size_t)blockIdx.x * 256 + threadIdx.x;
  const float4* s = (const float4*)src + i * 2;
  float4 a = s[0], b = s[1];
  short8 o;
  o[0] = (short)f2bf(a.x); o[1] = (short)f2bf(a.y); o[2] = (short)f2bf(a.z); o[3] = (short)f2bf(a.w);
  o[4] = (short)f2bf(b.x); o[5] = (short)f2bf(b.y); o[6] = (short)f2bf(b.z); o[7] = (short)f2bf(b.w);
  ((short8*)dst)[i] = o;
}

__global__ void __launch_bounds__(256) k_cvt_w(const float* __restrict__ Wq,
                                               const float* __restrict__ Wk,
                                               const float* __restrict__ Wv,
                                               unsigned short* __restrict__ dst) {
  size_t i = (size_t)blockIdx.x * 256 + threadIdx.x;
  int e = (int)(i * 8);
  int n = e >> 10, c = e & 1023;
  const float* row = (n < 1024) ? (Wq + (size_t)n * 1024)
                   : (n < 2048) ? (Wk + (size_t)(n - 1024) * 1024)
                                : (Wv + (size_t)(n - 2048) * 1024);
  const float4* s = (const float4*)(row + c);
  float4 a = s[0], b = s[1];
  short8 o;
  o[0] = (short)f2bf(a.x); o[1] = (short)f2bf(a.y); o[2] = (short)f2bf(a.z); o[3] = (short)f2bf(a.w);
  o[4] = (short)f2bf(b.x); o[5] = (short)f2bf(b.y); o[6] = (short)f2bf(b.z); o[7] = (short)f2bf(b.w);
  ((short8*)dst)[i] = o;
}

__global__ void __launch_bounds__(256) k_seg(const int* __restrict__ seg_ids,
                                             const float* __restrict__ seg_table,
                                             unsigned short* __restrict__ Kaug) {
  size_t i = (size_t)blockIdx.x * 256 + threadIdx.x;
  int e = (int)(i * 8);
  int jl = e >> 10;
  int r  = e & 1023;
  int sid = seg_ids[jl];
  const float4* s = (const float4*)(seg_table + (size_t)sid * 1024 + r);
  float4 a = s[0], b = s[1];
  short8 o;
  o[0] = (short)f2bf(a.x); o[1] = (short)f2bf(a.y); o[2] = (short)f2bf(a.z); o[3] = (short)f2bf(a.w);
  o[4] = (short)f2bf(b.x); o[5] = (short)f2bf(b.y); o[6] = (short)f2bf(b.z); o[7] = (short)f2bf(b.w);
  int b_ = jl >> 11, j = jl & 2047;
  int h = r >> 6, d = r & 63;
  size_t off = ((size_t)(b_ * 16 + h) * 2048 + j) * 128 + 64 + d;
  *(short8*)(Kaug + off) = o;
}

// ---------------- V transpose: [bh][S][64] -> [bh][64][S], k-axis permuted ----------------
// within each 32-k block, stored position of k (hi=bit4, gg=bits2-3, lo=bits0-1):
//   pos = gg*8 + hi*4 + lo   (so a b128 read at pos kb*32+g*8 yields the PV B-frag order)
__global__ void __launch_bounds__(256) k_vt(const unsigned short* __restrict__ V,
                                            unsigned short* __restrict__ Vt) {
  __shared__ unsigned short lt[64 * 72];
  int blk = blockIdx.x;
  int bh = blk >> 5, jt = blk & 31;
  int j0 = jt * 64;
  int tid = threadIdx.x;
  const char* src = (const char*)(V + ((size_t)bh * 2048 + j0) * 64);
#pragma unroll
  for (int it = 0; it < 2; ++it) {
    int c = tid + it * 256;
    int j = c >> 3, colb = (c & 7) * 16;
    int jpos = (j & 32) | ((((j >> 2) & 3) << 3) + (((j >> 4) & 1) << 2) + (j & 3));
    short8 v = *(const short8*)(src + (size_t)j * 128 + colb);
    int d0 = colb >> 1;
#pragma unroll
    for (int e = 0; e < 8; ++e)
      lt[(d0 + e) * 72 + jpos] = (unsigned short)v[e];
  }
  __syncthreads();
  char* dst = (char*)(Vt + (size_t)bh * 131072 + j0);
#pragma unroll
  for (int it = 0; it < 2; ++it) {
    int c = tid + it * 256;
    int d = c >> 3, jc = (c & 7) * 8;
    short8 o = *(const short8*)&lt[d * 72 + jc];
    *(short8*)(dst + (size_t)d * 4096 + jc * 2) = o;
  }
}

// ---------------- fused QKV GEMM (NT) ----------------
__global__ void __launch_bounds__(256) k_gemm(const unsigned short* __restrict__ A,
                                              const unsigned short* __restrict__ Bw,
                                              const float* __restrict__ bq,
                                              const float* __restrict__ bv,
                                              const float* __restrict__ bqs,
                                              unsigned short* __restrict__ Qaug,
                                              unsigned short* __restrict__ Kaug,
                                              unsigned short* __restrict__ Vo) {
  __shared__ unsigned short As[128 * 32];
  __shared__ unsigned short Bs[128 * 32];
  int n0 = blockIdx.x * 128;
  int m0 = blockIdx.y * 128;
  int tid = threadIdx.x;
  int w = tid >> 6, lane = tid & 63;
  int wr = (w >> 1) * 64, wc = (w & 1) * 64;
  int rA = lane & 15;
  int kg = (lane >> 4) * 16;
  f32x4 acc[4][4] = {};
  const char* Ab = (const char*)A;
  const char* Bb = (const char*)Bw;

  for (int kt = 0; kt < 32; ++kt) {
    int kb0 = kt * 64;
#pragma unroll
    for (int c = 0; c < 2; ++c) {
      int chunk = w * 2 + c;
      int y = chunk * 1024 + lane * 16;
      int row = y >> 6, colb = y & 63;
      gload16(Ab + (size_t)(m0 + row) * 2048 + kb0 + colb, (char*)As + chunk * 1024);
      gload16(Bb + (size_t)(n0 + row) * 2048 + kb0 + colb, (char*)Bs + chunk * 1024);
    }
    __syncthreads();
    short8 af[4], bfr[4];
#pragma unroll
    for (int m = 0; m < 4; ++m)
      af[m] = *(const short8*)((const char*)As + (wr + m * 16 + rA) * 64 + kg);
#pragma unroll
    for (int n = 0; n < 4; ++n)
      bfr[n] = *(const short8*)((const char*)Bs + (wc + n * 16 + rA) * 64 + kg);
#pragma unroll
    for (int m = 0; m < 4; ++m)
#pragma unroll
      for (int n = 0; n < 4; ++n)
        acc[m][n] = __builtin_amdgcn_mfma_f32_16x16x32_bf16(af[m], bfr[n], acc[m][n], 0, 0, 0);
    __syncthreads();
  }

  int seg = n0 >> 10;
  int colbase = n0 & 1023;
#pragma unroll
  for (int n = 0; n < 4; ++n) {
    int o = colbase + wc + n * 16 + (lane & 15);
    int h = o >> 6, d = o & 63;
    float bias = 0.f, bqsv = 0.f;
    if (seg == 0) { bias = bq[o]; bqsv = bqs[o]; }
    else if (seg == 2) { bias = bv[o]; }
#pragma unroll
    for (int m = 0; m < 4; ++m) {
#pragma unroll
      for (int r = 0; r < 4; ++r) {
        int i = m0 + wr + m * 16 + (lane >> 4) * 4 + r;
        int b_ = i >> 11, sdx = i & 2047;
        float val = acc[m][n][r];
        size_t tok = (size_t)(b_ * 16 + h) * 2048 + sdx;
        if (seg == 0) {
          float qv = val + bias;
          Qaug[tok * 128 + d]      = f2bf(qv * (0.125f * RLN2));
          Qaug[tok * 128 + 64 + d] = f2bf((qv + bqsv) * RLN2);
        } else if (seg == 1) {
          Kaug[tok * 128 + d] = f2bf(val);
        } else {
          Vo[tok * 64 + d] = f2bf(val + bias);
        }
      }
    }
  }
}

// ---------------- flash attention ----------------
// S^T layout (swapped MFMA): lane owns q = lane&15; s[jb][r] holds k = jb*16 + g*4 + r.
// K LDS layout [db][krow][32elem]: fragment addr = q16*64+g*16 (lane-const) + imm(db*4096+jb*1024),
//   bank slots = {krow&1, g} -> 2-way only (free), no swizzle.
// V LDS: [dv][64 k-permuted] rows, XOR swizzle bits4-6; one b128 per (nb,kb) at imm nb*2048.
__global__ void __launch_bounds__(256, 3) k_attn(const unsigned short* __restrict__ Qaug,
                                                 const unsigned short* __restrict__ Kaug,
                                                 const unsigned short* __restrict__ Vt,
                                                 const float* __restrict__ mask,
                                                 float* __restrict__ out) {
  __shared__ char smem[49152];
  char* Ksb = smem;          // 2 x 16K
  char* Vsb = smem + 32768;  // 2 x 8K

  int qt = blockIdx.x, h = blockIdx.y, b_ = blockIdx.z;
  int bh = b_ * 16 + h;
  int i0 = qt * 64;
  int tid = threadIdx.x, w = tid >> 6, lane = tid & 63;
  int q16 = lane & 15, g = lane >> 4;
  int swzq = (q16 & 7) << 4;
  const char* Qg = (const char*)Qaug + (size_t)bh * 2048 * 256;
  const char* Kg = (const char*)Kaug + (size_t)bh * 2048 * 256;
  const char* Vg = (const char*)Vt + (size_t)bh * 64 * 4096;
  const float* maskb = mask + (size_t)b_ * 2048;

  // lane-invariant staging offsets
  int kl_row = lane >> 2, kl_cb = (lane & 3) * 16;   // K: per-chunk row/byte
  int vl_dvl = lane >> 3, vl_bv = (lane & 7) * 16;   // V: per-chunk row/byte

  // ---- stage tile 0 ----
#pragma unroll
  for (int c = 0; c < 4; ++c) {
    int ck = w * 4 + c;
    int db = ck >> 2, rhi = (ck & 3) << 4;
    gload16(Kg + (size_t)(rhi + kl_row) * 256 + db * 64 + kl_cb, Ksb + ck * 1024);
  }
#pragma unroll
  for (int c = 0; c < 2; ++c) {
    int ck = w * 2 + c;
    int dv = ck * 8 + vl_dvl;
    gload16(Vg + (size_t)dv * 4096 + ((vl_bv ^ ((dv & 7) << 4)) & 127), Vsb + ck * 1024);
  }

  // Q fragments (B-operand) straight from global
  short8 qf[4];
  {
    const char* qrow = Qg + (size_t)(i0 + w * 16 + q16) * 256 + g * 16;
#pragma unroll
    for (int db = 0; db < 4; ++db)
      qf[db] = *(const short8*)(qrow + db * 64);
  }
  __syncthreads();  // K0/V0 resident

  float m_run = -1e30f, l_run = 0.f;
  f32x4 accO[4] = {};

  for (int t = 0; t < 32; ++t) {
    int cur = t & 1, nxt = cur ^ 1;
    int j0 = t * 64;
    if (t < 31) {
      int jn = j0 + 64;
      char* kd = Ksb + nxt * 16384;
      char* vd = Vsb + nxt * 8192;
#pragma unroll
      for (int c = 0; c < 4; ++c) {
        int ck = w * 4 + c;
        int db = ck >> 2, rhi = (ck & 3) << 4;
        gload16(Kg + (size_t)(jn + rhi + kl_row) * 256 + db * 64 + kl_cb, kd + ck * 1024);
      }
#pragma unroll
      for (int c = 0; c < 2; ++c) {
        int ck = w * 2 + c;
        int dv = ck * 8 + vl_dvl;
        gload16(Vg + (size_t)dv * 4096 + jn * 2 + ((vl_bv ^ ((dv & 7) << 4)) & 127),
                vd + ck * 1024);
      }
    }
    const char* kbase = Ksb + cur * 16384 + q16 * 64 + g * 16;
    const char* vb_ = Vsb + cur * 8192;
    const char* vbase0 = vb_ + ((q16 * 128 + g * 16) ^ swzq);
    const char* vbase1 = vb_ + ((q16 * 128 + 64 + g * 16) ^ swzq);

    // ---- S^T = K_aug . Q_aug^T ----
    f32x4 s[4] = {};
    __builtin_amdgcn_s_setprio(1);
#pragma unroll
    for (int jb = 0; jb < 4; ++jb) {
#pragma unroll
      for (int db = 0; db < 4; ++db) {
        short8 kf = *(const short8*)(kbase + db * 4096 + jb * 1024);
        s[jb] = __builtin_amdgcn_mfma_f32_16x16x32_bf16(kf, qf[db], s[jb], 0, 0, 0);
      }
    }
    __builtin_amdgcn_s_setprio(0);

    // ---- mask add (vectorized, pk-f32) ----
#pragma unroll
    for (int jb = 0; jb < 4; ++jb) {
      f32x4 mv = *(const f32x4*)(maskb + j0 + jb * 16 + g * 4);
      s[jb] = s[jb] + mv * RLN2;
    }

    // ---- online softmax, lane-local (reduce across g: xor 16,32) ----
    float tm = fmaxf(fmaxf(s[0][0], s[0][1]), s[0][2]);
    tm = fmaxf(fmaxf(tm, s[0][3]), fmaxf(s[1][0], s[1][1]));
    tm = fmaxf(fmaxf(tm, s[1][2]), fmaxf(s[1][3], s[2][0]));
    tm = fmaxf(fmaxf(tm, s[2][1]), fmaxf(s[2][2], s[2][3]));
    tm = fmaxf(fmaxf(tm, s[3][0]), fmaxf(s[3][1], s[3][2]));
    tm = fmaxf(tm, s[3][3]);
    tm = fmaxf(tm, __shfl_xor(tm, 16));
    tm = fmaxf(tm, __shfl_xor(tm, 32));

    if (__any(tm > m_run + 8.0f)) {  // defer-max (T13)
      float mn = fmaxf(m_run, tm);
      float alpha = fast_exp2(m_run - mn);
      m_run = mn;
      l_run *= alpha;
      float al[4];
#pragma unroll
      for (int r = 0; r < 4; ++r)
        al[r] = __shfl(alpha, (lane & 48) + g * 4 + r);
#pragma unroll
      for (int nb = 0; nb < 4; ++nb) {
        accO[nb][0] *= al[0]; accO[nb][1] *= al[1];
        accO[nb][2] *= al[2]; accO[nb][3] *= al[3];
      }
    }

    f32x4 pssum = {0.f, 0.f, 0.f, 0.f};
#pragma unroll
    for (int jb = 0; jb < 4; ++jb) {
      f32x4 x = s[jb] - m_run;
      f32x4 e;
      e[0] = fast_exp2(x[0]); e[1] = fast_exp2(x[1]);
      e[2] = fast_exp2(x[2]); e[3] = fast_exp2(x[3]);
      s[jb] = e;
      pssum = pssum + e;
    }
    float ps = (pssum[0] + pssum[1]) + (pssum[2] + pssum[3]);
    ps += __shfl_xor(ps, 16);
    ps += __shfl_xor(ps, 32);
    l_run += ps;

    // ---- pack P via v_cvt_pk_bf16_f32 (8 instrs) ----
    unsigned int pk[4][2];
#pragma unroll
    for (int jb = 0; jb < 4; ++jb) {
      pk[jb][0] = cvt_pk_bf16(s[jb][0], s[jb][1]);
      pk[jb][1] = cvt_pk_bf16(s[jb][2], s[jb][3]);
    }

    // ---- O += P . V (permuted contraction axis) ----
    __builtin_amdgcn_s_setprio(1);
#pragma unroll
    for (int kb = 0; kb < 2; ++kb) {
      uint4v pw;
      pw[0] = pk[2 * kb][0]; pw[1] = pk[2 * kb][1];
      pw[2] = pk[2 * kb + 1][0]; pw[3] = pk[2 * kb + 1][1];
      short8 pf = __builtin_bit_cast(short8, pw);
      const char* vbase = kb ? vbase1 : vbase0;
#pragma unroll
      for (int nb = 0; nb < 4; ++nb) {
        short8 vf = *(const short8*)(vbase + nb * 2048);
        accO[nb] = __builtin_amdgcn_mfma_f32_16x16x32_bf16(pf, vf, accO[nb], 0, 0, 0);
      }
    }
    __builtin_amdgcn_s_setprio(0);
    __syncthreads();
  }

  float lr[4];
#pragma unroll
  for (int r = 0; r < 4; ++r)
    lr[r] = 1.0f / __shfl(l_run, (lane & 48) + g * 4 + r);
#pragma unroll
  for (int nb = 0; nb < 4; ++nb) {
    int dv = nb * 16 + q16;
#pragma unroll
    for (int r = 0; r < 4; ++r) {
      int i = i0 + w * 16 + g * 4 + r;
      out[((size_t)b_ * 2048 + i) * 1024 + h * 64 + dv] = accO[nb][r] * lr[r];
    }
  }
}

extern "C" void kernel_launch(void* const* d_in, const int* in_sizes, int n_in,
                              void* d_out, int out_size, void* d_ws, size_t ws_size,
                              hipStream_t stream) {
  (void)in_sizes; (void)n_in; (void)out_size; (void)ws_size;
  const float* hs        = (const float*)d_in[0];
  const float* mask      = (const float*)d_in[1];
  const int*   seg_ids   = (const int*)d_in[2];
  const float* Wq        = (const float*)d_in[3];
  const float* bq        = (const float*)d_in[4];
  const float* Wk        = (const float*)d_in[5];
  const float* Wv        = (const float*)d_in[6];
  const float* bv        = (const float*)d_in[7];
  const float* seg_table = (const float*)d_in[8];
  const float* bqs       = (const float*)d_in[9];
  float* out = (float*)d_out;
  char* ws = (char*)d_ws;

  unsigned short* hsb  = (unsigned short*)(ws + 0);         // 16 MiB
  unsigned short* Wcat = (unsigned short*)(ws + 16777216);  // 6 MiB
  unsigned short* Qaug = (unsigned short*)(ws + 23068672);  // 32 MiB
  unsigned short* Kaug = (unsigned short*)(ws + 56623104);  // 32 MiB
  unsigned short* V    = (unsigned short*)(ws + 90177536);  // 16 MiB
  unsigned short* Vt   = (unsigned short*)(ws + 0);         // reuse (hsb dead after GEMM)

  k_cvt_hs<<<dim3(4096), dim3(256), 0, stream>>>(hs, hsb);
  k_cvt_w<<<dim3(1536), dim3(256), 0, stream>>>(Wq, Wk, Wv, Wcat);
  k_gemm<<<dim3(24, 64), dim3(256), 0, stream>>>(hsb, Wcat, bq, bv, bqs, Qaug, Kaug, V);
  k_seg<<<dim3(4096), dim3(256), 0, stream>>>(seg_ids, seg_table, Kaug);
  k_vt<<<dim3(2048), dim3(256), 0, stream>>>(V, Vt);
  k_attn<<<dim3(32, 16, 4), dim3(256), 0, stream>>>(Qaug, Kaug, Vt, mask, out);
}

// Round 4
// 280.389 us; speedup vs baseline: 1.4460x; 1.0616x over previous
//
#include <hip/hip_runtime.h>
#include <cstdint>
#include <cmath>

#define RLN2 1.44269504088896340736f

typedef __attribute__((ext_vector_type(8))) short short8;
typedef __attribute__((ext_vector_type(4))) float f32x4;
typedef __attribute__((ext_vector_type(16))) float f32x16;
typedef __attribute__((ext_vector_type(4))) unsigned int uint4v;

__device__ __forceinline__ unsigned short f2bf(float f) {
  unsigned int u = __float_as_uint(f);
  u += 0x7fffu + ((u >> 16) & 1u);
  return (unsigned short)(u >> 16);
}

__device__ __forceinline__ unsigned int cvt_pk_bf16(float lo, float hi) {
  unsigned int r;
  asm("v_cvt_pk_bf16_f32 %0, %1, %2" : "=v"(r) : "v"(lo), "v"(hi));
  return r;
}

__device__ __forceinline__ float fast_exp2(float x) {
#if __has_builtin(__builtin_amdgcn_exp2f)
  return __builtin_amdgcn_exp2f(x);
#else
  return exp2f(x);
#endif
}

__device__ __forceinline__ void gload16(const void* g, void* l) {
  __builtin_amdgcn_global_load_lds(
      (const __attribute__((address_space(1))) unsigned int*)g,
      (__attribute__((address_space(3))) unsigned int*)l,
      16, 0, 0);
}

// ---------------- fp32 -> bf16 conversions ----------------

__global__ void __launch_bounds__(256) k_cvt_hs(const float* __restrict__ src,
                                                unsigned short* __restrict__ dst) {
  size_t i = (size_t)blockIdx.x * 256 + threadIdx.x;
  const float4* s = (const float4*)src + i * 2;
  float4 a = s[0], b = s[1];
  short8 o;
  o[0] = (short)f2bf(a.x); o[1] = (short)f2bf(a.y); o[2] = (short)f2bf(a.z); o[3] = (short)f2bf(a.w);
  o[4] = (short)f2bf(b.x); o[5] = (short)f2bf(b.y); o[6] = (short)f2bf(b.z); o[7] = (short)f2bf(b.w);
  ((short8*)dst)[i] = o;
}

__global__ void __launch_bounds__(256) k_cvt_w(const float* __restrict__ Wq,
                                               const float* __restrict__ Wk,
                                               const float* __restrict__ Wv,
                                               unsigned short* __restrict__ dst) {
  size_t i = (size_t)blockIdx.x * 256 + threadIdx.x;
  int e = (int)(i * 8);
  int n = e >> 10, c = e & 1023;
  const float* row = (n < 1024) ? (Wq + (size_t)n * 1024)
                   : (n < 2048) ? (Wk + (size_t)(n - 1024) * 1024)
                                : (Wv + (size_t)(n - 2048) * 1024);
  const float4* s = (const float4*)(row + c);
  float4 a = s[0], b = s[1];
  short8 o;
  o[0] = (short)f2bf(a.x); o[1] = (short)f2bf(a.y); o[2] = (short)f2bf(a.z); o[3] = (short)f2bf(a.w);
  o[4] = (short)f2bf(b.x); o[5] = (short)f2bf(b.y); o[6] = (short)f2bf(b.z); o[7] = (short)f2bf(b.w);
  ((short8*)dst)[i] = o;
}

__global__ void __launch_bounds__(256) k_seg(const int* __restrict__ seg_ids,
                                             const float* __restrict__ seg_table,
                                             unsigned short* __restrict__ Kaug) {
  size_t i = (size_t)blockIdx.x * 256 + threadIdx.x;
  int e = (int)(i * 8);
  int jl = e >> 10;
  int r  = e & 1023;
  int sid = seg_ids[jl];
  const float4* s = (const float4*)(seg_table + (size_t)sid * 1024 + r);
  float4 a = s[0], b = s[1];
  short8 o;
  o[0] = (short)f2bf(a.x); o[1] = (short)f2bf(a.y); o[2] = (short)f2bf(a.z); o[3] = (short)f2bf(a.w);
  o[4] = (short)f2bf(b.x); o[5] = (short)f2bf(b.y); o[6] = (short)f2bf(b.z); o[7] = (short)f2bf(b.w);
  int b_ = jl >> 11, j = jl & 2047;
  int h = r >> 6, d = r & 63;
  size_t off = ((size_t)(b_ * 16 + h) * 2048 + j) * 128 + 64 + d;
  *(short8*)(Kaug + off) = o;
}

// ---------------- V transpose: [bh][S][64] -> [bh][64][S], k-axis permuted ----------------
// stored pos p within each 64-k block holds true k where (kh=k>>5, c=(k>>3)&3,
// hi=(k>>2)&1, r=k&3):  p = (2*kh + (c>>1))*16 + 8*hi + 4*(c&1) + r
// so the PV A-fragment read (pos = ks*16 + 8*hi + e) matches P packed from
// consecutive S^T regs (reg = e + 8*(ks&1) of s[ks>>1]).
__global__ void __launch_bounds__(256) k_vt(const unsigned short* __restrict__ V,
                                            unsigned short* __restrict__ Vt) {
  __shared__ unsigned short lt[64 * 72];
  int blk = blockIdx.x;
  int bh = blk >> 5, jt = blk & 31;
  int j0 = jt * 64;
  int tid = threadIdx.x;
  const char* src = (const char*)(V + ((size_t)bh * 2048 + j0) * 64);
#pragma unroll
  for (int it = 0; it < 2; ++it) {
    int c = tid + it * 256;
    int j = c >> 3, colb = (c & 7) * 16;
    int kh2 = (j >> 5) & 1, c2 = (j >> 3) & 3, hi2 = (j >> 2) & 1, r2 = j & 3;
    int jpos = (2 * kh2 + (c2 >> 1)) * 16 + 8 * hi2 + 4 * (c2 & 1) + r2;
    short8 v = *(const short8*)(src + (size_t)j * 128 + colb);
    int d0 = colb >> 1;
#pragma unroll
    for (int e = 0; e < 8; ++e)
      lt[(d0 + e) * 72 + jpos] = (unsigned short)v[e];
  }
  __syncthreads();
  char* dst = (char*)(Vt + (size_t)bh * 131072 + j0);
#pragma unroll
  for (int it = 0; it < 2; ++it) {
    int c = tid + it * 256;
    int d = c >> 3, jc = (c & 7) * 8;
    short8 o = *(const short8*)&lt[d * 72 + jc];
    *(short8*)(dst + (size_t)d * 4096 + jc * 2) = o;
  }
}

// ---------------- fused QKV GEMM (NT) ----------------
__global__ void __launch_bounds__(256) k_gemm(const unsigned short* __restrict__ A,
                                              const unsigned short* __restrict__ Bw,
                                              const float* __restrict__ bq,
                                              const float* __restrict__ bv,
                                              const float* __restrict__ bqs,
                                              unsigned short* __restrict__ Qaug,
                                              unsigned short* __restrict__ Kaug,
                                              unsigned short* __restrict__ Vo) {
  __shared__ unsigned short As[128 * 32];
  __shared__ unsigned short Bs[128 * 32];
  int n0 = blockIdx.x * 128;
  int m0 = blockIdx.y * 128;
  int tid = threadIdx.x;
  int w = tid >> 6, lane = tid & 63;
  int wr = (w >> 1) * 64, wc = (w & 1) * 64;
  int rA = lane & 15;
  int kg = (lane >> 4) * 16;
  f32x4 acc[4][4] = {};
  const char* Ab = (const char*)A;
  const char* Bb = (const char*)Bw;

  for (int kt = 0; kt < 32; ++kt) {
    int kb0 = kt * 64;
#pragma unroll
    for (int c = 0; c < 2; ++c) {
      int chunk = w * 2 + c;
      int y = chunk * 1024 + lane * 16;
      int row = y >> 6, colb = y & 63;
      gload16(Ab + (size_t)(m0 + row) * 2048 + kb0 + colb, (char*)As + chunk * 1024);
      gload16(Bb + (size_t)(n0 + row) * 2048 + kb0 + colb, (char*)Bs + chunk * 1024);
    }
    __syncthreads();
    short8 af[4], bfr[4];
#pragma unroll
    for (int m = 0; m < 4; ++m)
      af[m] = *(const short8*)((const char*)As + (wr + m * 16 + rA) * 64 + kg);
#pragma unroll
    for (int n = 0; n < 4; ++n)
      bfr[n] = *(const short8*)((const char*)Bs + (wc + n * 16 + rA) * 64 + kg);
#pragma unroll
    for (int m = 0; m < 4; ++m)
#pragma unroll
      for (int n = 0; n < 4; ++n)
        acc[m][n] = __builtin_amdgcn_mfma_f32_16x16x32_bf16(af[m], bfr[n], acc[m][n], 0, 0, 0);
    __syncthreads();
  }

  int seg = n0 >> 10;
  int colbase = n0 & 1023;
#pragma unroll
  for (int n = 0; n < 4; ++n) {
    int o = colbase + wc + n * 16 + (lane & 15);
    int h = o >> 6, d = o & 63;
    float bias = 0.f, bqsv = 0.f;
    if (seg == 0) { bias = bq[o]; bqsv = bqs[o]; }
    else if (seg == 2) { bias = bv[o]; }
#pragma unroll
    for (int m = 0; m < 4; ++m) {
#pragma unroll
      for (int r = 0; r < 4; ++r) {
        int i = m0 + wr + m * 16 + (lane >> 4) * 4 + r;
        int b_ = i >> 11, sdx = i & 2047;
        float val = acc[m][n][r];
        size_t tok = (size_t)(b_ * 16 + h) * 2048 + sdx;
        if (seg == 0) {
          float qv = val + bias;
          Qaug[tok * 128 + d]      = f2bf(qv * (0.125f * RLN2));
          Qaug[tok * 128 + 64 + d] = f2bf((qv + bqsv) * RLN2);
        } else if (seg == 1) {
          Kaug[tok * 128 + d] = f2bf(val);
        } else {
          Vo[tok * 64 + d] = f2bf(val + bias);
        }
      }
    }
  }
}

// ---------------- flash attention, 32x32x16 MFMA, 32 q-rows/wave ----------------
// S^T = mfma(A=K, B=Q): lane owns q = lane&31; s[kh][reg] holds
//   k = kh*32 + 4*hi + (reg&3) + 8*(reg>>2)   (hi = lane>>5)
// PV:  O = mfma(A=Vt-frag, B=P): A rows = dv (Vt is [dv][S]), cols = q.
// P B-frag for k-step ks is simply regs e+8*(ks&1) of s[ks>>1] thanks to the
// k-permuted Vt storage (see k_vt). accO[vh][reg]: dv = vh*32+4*hi+(reg&3)+8*(reg>>2).
// LDS: K [64 rows][256B] rows swizzled ^((row&7)<<4); V [64 dv][128B] ^((dv&7)<<4);
// each 16-lane b128 phase hits every bank-granule exactly 2x (minimum).
__global__ void __launch_bounds__(256, 3) k_attn(const unsigned short* __restrict__ Qaug,
                                                 const unsigned short* __restrict__ Kaug,
                                                 const unsigned short* __restrict__ Vt,
                                                 const float* __restrict__ mask,
                                                 float* __restrict__ out) {
  __shared__ char smem[49152];
  char* Ksb = smem;          // 2 x 16K
  char* Vsb = smem + 32768;  // 2 x 8K

  int qt = blockIdx.x, h = blockIdx.y, b_ = blockIdx.z;
  int bh = b_ * 16 + h;
  int i0 = qt * 128;
  int tid = threadIdx.x, w = tid >> 6, lane = tid & 63;
  int q = lane & 31, hi = lane >> 5;
  int swzq = (q & 7) << 4;
  const char* Qg = (const char*)Qaug + (size_t)bh * 2048 * 256;
  const char* Kg = (const char*)Kaug + (size_t)bh * 2048 * 256;
  const char* Vg = (const char*)Vt + (size_t)bh * 64 * 4096;
  const float* maskb = mask + (size_t)b_ * 2048;

  // tile-invariant fragment byte offsets (within a K row / V row)
  int foff[8];
#pragma unroll
  for (int ds = 0; ds < 8; ++ds)
    foff[ds] = (ds * 32 + hi * 16) ^ swzq;

  // staging lane decomps
  int kst_row = lane >> 4, kst_x = (lane & 15) * 16;
  int vst_dv = lane >> 3;
  int vst_x = ((lane & 7) * 16) ^ ((vst_dv & 7) << 4);

  // ---- stage tile 0 ----
#pragma unroll
  for (int c = 0; c < 4; ++c) {
    int ck = w * 4 + c;
    int krow = ck * 4 + kst_row;
    gload16(Kg + (size_t)krow * 256 + (kst_x ^ ((krow & 7) << 4)), Ksb + ck * 1024);
  }
#pragma unroll
  for (int c = 0; c < 2; ++c) {
    int ck = w * 2 + c;
    int dv = ck * 8 + vst_dv;
    gload16(Vg + (size_t)dv * 4096 + vst_x, Vsb + ck * 1024);
  }

  // Q fragments (B-operand): row = i0 + w*32 + q, 8 x 16B at ds*32 + hi*16
  short8 qf[8];
  {
    const char* qrow = Qg + (size_t)(i0 + w * 32 + q) * 256 + hi * 16;
#pragma unroll
    for (int ds = 0; ds < 8; ++ds)
      qf[ds] = *(const short8*)(qrow + ds * 32);
  }
  __syncthreads();  // K0/V0 resident

  float m_run = -1e30f, l_run = 0.f;
  f32x16 accO[2] = {};

  for (int t = 0; t < 32; ++t) {
    int cur = t & 1, nxt = cur ^ 1;
    int j0 = t * 64;
    if (t < 31) {
      int jn = j0 + 64;
      char* kd = Ksb + nxt * 16384;
      char* vd = Vsb + nxt * 8192;
#pragma unroll
      for (int c = 0; c < 4; ++c) {
        int ck = w * 4 + c;
        int krow = ck * 4 + kst_row;
        gload16(Kg + (size_t)(jn + krow) * 256 + (kst_x ^ ((krow & 7) << 4)), kd + ck * 1024);
      }
#pragma unroll
      for (int c = 0; c < 2; ++c) {
        int ck = w * 2 + c;
        int dv = ck * 8 + vst_dv;
        gload16(Vg + (size_t)dv * 4096 + jn * 2 + vst_x, vd + ck * 1024);
      }
    }
    const char* kq = Ksb + cur * 16384 + q * 256;
    const char* vq = Vsb + cur * 8192 + q * 128;

    // ---- S^T = K . Q^T (two 32x32 k-halves, 8 d-steps) ----
    f32x16 s0 = {}, s1 = {};
    __builtin_amdgcn_s_setprio(1);
#pragma unroll
    for (int ds = 0; ds < 8; ++ds) {
      short8 kf0 = *(const short8*)(kq + foff[ds]);
      short8 kf1 = *(const short8*)(kq + foff[ds] + 8192);
      s0 = __builtin_amdgcn_mfma_f32_32x32x16_bf16(kf0, qf[ds], s0, 0, 0, 0);
      s1 = __builtin_amdgcn_mfma_f32_32x32x16_bf16(kf1, qf[ds], s1, 0, 0, 0);
    }
    __builtin_amdgcn_s_setprio(0);

    // ---- mask add: s*[4c+r] is k = kh*32 + 4*hi + r + 8*c ----
#pragma unroll
    for (int c = 0; c < 4; ++c) {
      f32x4 mv0 = *(const f32x4*)(maskb + j0 + 8 * c + 4 * hi);
      f32x4 mv1 = *(const f32x4*)(maskb + j0 + 32 + 8 * c + 4 * hi);
#pragma unroll
      for (int r = 0; r < 4; ++r) {
        s0[4 * c + r] += mv0[r] * RLN2;
        s1[4 * c + r] += mv1[r] * RLN2;
      }
    }

    // ---- online softmax: lane owns q; reduce across hi via xor 32 ----
    float tm = -1e30f;
#pragma unroll
    for (int i = 0; i < 16; ++i) tm = fmaxf(tm, fmaxf(s0[i], s1[i]));
    tm = fmaxf(tm, __shfl_xor(tm, 32));

    if (__any(tm > m_run + 8.0f)) {  // defer-max (T13)
      float mn = fmaxf(m_run, tm);
      float alpha = fast_exp2(m_run - mn);
      m_run = mn;
      l_run *= alpha;
#pragma unroll
      for (int i = 0; i < 16; ++i) { accO[0][i] *= alpha; accO[1][i] *= alpha; }
    }

    float ps = 0.f;
#pragma unroll
    for (int i = 0; i < 16; ++i) {
      float e0 = fast_exp2(s0[i] - m_run);
      float e1 = fast_exp2(s1[i] - m_run);
      s0[i] = e0; s1[i] = e1;
      ps += e0 + e1;
    }
    ps += __shfl_xor(ps, 32);
    l_run += ps;

    // ---- pack P: B-frag for k-step ks = regs e+8*(ks&1) of s[ks>>1] ----
    uint4v pk[4];
#pragma unroll
    for (int ks = 0; ks < 4; ++ks) {
      int o = 8 * (ks & 1);
      const f32x16& sv = (ks < 2) ? s0 : s1;
      pk[ks][0] = cvt_pk_bf16(sv[o + 0], sv[o + 1]);
      pk[ks][1] = cvt_pk_bf16(sv[o + 2], sv[o + 3]);
      pk[ks][2] = cvt_pk_bf16(sv[o + 4], sv[o + 5]);
      pk[ks][3] = cvt_pk_bf16(sv[o + 6], sv[o + 7]);
    }

    // ---- O += Vt-frag . P  (4 k-steps x 2 dv-halves) ----
    __builtin_amdgcn_s_setprio(1);
#pragma unroll
    for (int ks = 0; ks < 4; ++ks) {
      short8 pf = __builtin_bit_cast(short8, pk[ks]);
      short8 vf0 = *(const short8*)(vq + foff[ks]);
      short8 vf1 = *(const short8*)(vq + foff[ks] + 4096);
      accO[0] = __builtin_amdgcn_mfma_f32_32x32x16_bf16(vf0, pf, accO[0], 0, 0, 0);
      accO[1] = __builtin_amdgcn_mfma_f32_32x32x16_bf16(vf1, pf, accO[1], 0, 0, 0);
    }
    __builtin_amdgcn_s_setprio(0);
    __syncthreads();  // prefetch drained; buffers swap
  }

  float inv = 1.0f / l_run;
  float* orow = out + ((size_t)b_ * 2048 + i0 + w * 32 + q) * 1024 + h * 64;
#pragma unroll
  for (int vh = 0; vh < 2; ++vh) {
#pragma unroll
    for (int c = 0; c < 4; ++c) {
      f32x4 o;
      o[0] = accO[vh][4 * c + 0] * inv;
      o[1] = accO[vh][4 * c + 1] * inv;
      o[2] = accO[vh][4 * c + 2] * inv;
      o[3] = accO[vh][4 * c + 3] * inv;
      *(f32x4*)(orow + vh * 32 + 8 * c + 4 * hi) = o;
    }
  }
}

extern "C" void kernel_launch(void* const* d_in, const int* in_sizes, int n_in,
                              void* d_out, int out_size, void* d_ws, size_t ws_size,
                              hipStream_t stream) {
  (void)in_sizes; (void)n_in; (void)out_size; (void)ws_size;
  const float* hs        = (const float*)d_in[0];
  const float* mask      = (const float*)d_in[1];
  const int*   seg_ids   = (const int*)d_in[2];
  const float* Wq        = (const float*)d_in[3];
  const float* bq        = (const float*)d_in[4];
  const float* Wk        = (const float*)d_in[5];
  const float* Wv        = (const float*)d_in[6];
  const float* bv        = (const float*)d_in[7];
  const float* seg_table = (const float*)d_in[8];
  const float* bqs       = (const float*)d_in[9];
  float* out = (float*)d_out;
  char* ws = (char*)d_ws;

  unsigned short* hsb  = (unsigned short*)(ws + 0);         // 16 MiB
  unsigned short* Wcat = (unsigned short*)(ws + 16777216);  // 6 MiB
  unsigned short* Qaug = (unsigned short*)(ws + 23068672);  // 32 MiB
  unsigned short* Kaug = (unsigned short*)(ws + 56623104);  // 32 MiB
  unsigned short* V    = (unsigned short*)(ws + 90177536);  // 16 MiB
  unsigned short* Vt   = (unsigned short*)(ws + 0);         // reuse (hsb dead after GEMM)

  k_cvt_hs<<<dim3(4096), dim3(256), 0, stream>>>(hs, hsb);
  k_cvt_w<<<dim3(1536), dim3(256), 0, stream>>>(Wq, Wk, Wv, Wcat);
  k_gemm<<<dim3(24, 64), dim3(256), 0, stream>>>(hsb, Wcat, bq, bv, bqs, Qaug, Kaug, V);
  k_seg<<<dim3(4096), dim3(256), 0, stream>>>(seg_ids, seg_table, Kaug);
  k_vt<<<dim3(2048), dim3(256), 0, stream>>>(V, Vt);
  k_attn<<<dim3(16, 16, 4), dim3(256), 0, stream>>>(Qaug, Kaug, Vt, mask, out);
}